// Round 3
// baseline (172.583 us; speedup 1.0000x reference)
//
#include <hip/hip_runtime.h>
#include <math.h>

#define Bsz  2
#define Ntok 256
#define Ddim 512
#define Hdim 2048
#define Mrows (Bsz * Ntok)   // 512

typedef __bf16 bf16_8 __attribute__((ext_vector_type(8)));
typedef __bf16 bf16_4 __attribute__((ext_vector_type(4)));
typedef float  f32x4_t __attribute__((ext_vector_type(4)));

// ---------------------------------------------------------------------------
// Fused prep kernel.
// Blocks [0, 4608):   weight transpose+cast fp32 [K][N] -> bf16 [N][K]
// Blocks [4608, 4864): pairwise Manhattan distance row/col means (dv, da)
// ---------------------------------------------------------------------------
struct PrepPtrs {
    const float* src[5];
    __bf16*      dst[5];
    const float* xv;
    const float* xa;
    float*       dv;
    float*       da;
};

__global__ __launch_bounds__(256) void prep_kernel(PrepPtrs p) {
    __shared__ float tile[32][33];   // transpose staging
    __shared__ float red[4][4];      // dist reduction

    int blk = blockIdx.x;
    int tid = threadIdx.x;

    if (blk < 4608) {
        // ---- transpose+cast ----
        // W1v[512][2048], W1a[512][2048], Wmv[2048][512], Wma[2048][512], Wout[1024][512]
        const int Ks[5]  = {512, 512, 2048, 2048, 1024};
        const int Ns[5]  = {2048, 2048, 512, 512, 512};
        const int off[6] = {0, 1024, 2048, 3072, 4096, 4608};
        int mi = 0;
        while (blk >= off[mi + 1]) ++mi;
        int local = blk - off[mi];
        int shift = (mi < 2) ? 6 : 4;         // N/32
        int bx = local & ((1 << shift) - 1);
        int by = local >> shift;
        const float* src = p.src[mi];
        __bf16*      dst = p.dst[mi];
        int K = Ks[mi], N = Ns[mi];
        int n0 = bx << 5, k0 = by << 5;

        int kl = tid >> 3, nl = (tid & 7) << 2;
        float4 v = *(const float4*)&src[(size_t)(k0 + kl) * N + n0 + nl];
        tile[kl][nl + 0] = v.x;
        tile[kl][nl + 1] = v.y;
        tile[kl][nl + 2] = v.z;
        tile[kl][nl + 3] = v.w;
        __syncthreads();
        int nl2 = tid >> 3, kl2 = (tid & 7) << 2;
        bf16_4 o;
#pragma unroll
        for (int i = 0; i < 4; ++i) o[i] = (__bf16)tile[kl2 + i][nl2];
        *(bf16_4*)&dst[(size_t)(n0 + nl2) * K + k0 + kl2] = o;
    } else {
        // ---- distance means ----
        int bx   = blk - 4608;
        int role = bx >> 7;           // 0: dv, 1: da
        int g    = bx & 127;
        int b    = g >> 6;
        int i0   = (g & 63) << 2;
        const float* Q    = role ? p.xa : p.xv;
        const float* S    = role ? p.xv : p.xa;
        float*       outp = role ? p.da : p.dv;

        int t0 = tid, t1 = tid + 256;
        const float* Qb = Q + ((size_t)b * Ntok + i0) * Ddim;
        const float* Sb = S + (size_t)b * Ntok * Ddim;

        float q0[4], q1[4];
#pragma unroll
        for (int r = 0; r < 4; ++r) {
            q0[r] = Qb[r * Ddim + t0];
            q1[r] = Qb[r * Ddim + t1];
        }
        float acc[4] = {0.f, 0.f, 0.f, 0.f};
#pragma unroll 4
        for (int j = 0; j < Ntok; ++j) {
            float s0 = Sb[j * Ddim + t0];
            float s1 = Sb[j * Ddim + t1];
#pragma unroll
            for (int r = 0; r < 4; ++r)
                acc[r] += fabsf(q0[r] - s0) + fabsf(q1[r] - s1);
        }
        int lane = tid & 63, wv = tid >> 6;
#pragma unroll
        for (int r = 0; r < 4; ++r) {
            float v = acc[r];
#pragma unroll
            for (int off2 = 32; off2; off2 >>= 1) v += __shfl_down(v, off2);
            if (lane == 0) red[wv][r] = v;
        }
        __syncthreads();
        if (tid < 4) {
            float v = red[0][tid] + red[1][tid] + red[2][tid] + red[3][tid];
            outp[b * Ntok + i0 + tid] = v * (1.0f / 256.0f);
        }
    }
}

// ---------------------------------------------------------------------------
// bf16 MFMA GEMM, software-pipelined (ping-pong LDS, 1 barrier/iter,
// next tile's global loads issued before current tile's MFMAs).
// C[z] = act( (diag(scale[z]) * A[z]) @ B[z] + bias[z] )
// 64x64 tile, BK=32, 4 waves, each wave a 32x32 quadrant via 2x2 MFMA.
// ---------------------------------------------------------------------------
struct GPtrs {
    const void*   A[2];
    const __bf16* BT[2];
    const float*  bias[2];
    const float*  scale[2];
    void*         C[2];
};

template <int GELU, int AFP32, int OUTBF16>
__global__ __launch_bounds__(256) void mfma_gemm(GPtrs p, int Kdim, int ldc) {
    __shared__ __align__(16) __bf16 As[2][64][40];  // [buf][m][k], +8 pad
    __shared__ __align__(16) __bf16 Bs[2][64][40];  // [buf][n][k]

    const int zi  = blockIdx.z;
    const int tid = threadIdx.x;
    const int m0 = blockIdx.y << 6, n0 = blockIdx.x << 6;

    const int row = tid >> 2;        // 0..63
    const int kc  = (tid & 3) << 3;  // 0,8,16,24

    const __bf16* Bp = p.BT[zi] + (size_t)(n0 + row) * Kdim + kc;
    const float*  Afp = nullptr;
    const __bf16* Abp = nullptr;
    float s = 1.0f;
    if (AFP32) {
        Afp = (const float*)p.A[zi] + (size_t)(m0 + row) * Kdim + kc;
        s = p.scale[zi][m0 + row];
    } else {
        Abp = (const __bf16*)p.A[zi] + (size_t)(m0 + row) * Kdim + kc;
    }

    const int wave = tid >> 6, lane = tid & 63;
    const int moff = (wave >> 1) << 5, noff = (wave & 1) << 5;
    const int lrow = lane & 15, quad = lane >> 4;

    f32x4_t acc00 = {0.f, 0.f, 0.f, 0.f};
    f32x4_t acc01 = {0.f, 0.f, 0.f, 0.f};
    f32x4_t acc10 = {0.f, 0.f, 0.f, 0.f};
    f32x4_t acc11 = {0.f, 0.f, 0.f, 0.f};

    auto loadA = [&](int kt) -> bf16_8 {
        bf16_8 a8;
        if (AFP32) {
            float4 f0 = *(const float4*)(Afp + kt);
            float4 f1 = *(const float4*)(Afp + kt + 4);
            a8[0] = (__bf16)(f0.x * s); a8[1] = (__bf16)(f0.y * s);
            a8[2] = (__bf16)(f0.z * s); a8[3] = (__bf16)(f0.w * s);
            a8[4] = (__bf16)(f1.x * s); a8[5] = (__bf16)(f1.y * s);
            a8[6] = (__bf16)(f1.z * s); a8[7] = (__bf16)(f1.w * s);
        } else {
            a8 = *(const bf16_8*)(Abp + kt);
        }
        return a8;
    };

    // prologue: stage tile 0
    bf16_8 a_n = loadA(0);
    bf16_8 b_n = *(const bf16_8*)(Bp);
    *(bf16_8*)&As[0][row][kc] = a_n;
    *(bf16_8*)&Bs[0][row][kc] = b_n;
    __syncthreads();

    const int nIter = Kdim >> 5;
    for (int it = 0; it < nIter; ++it) {
        const int cur = it & 1;
        if (it + 1 < nIter) {
            a_n = loadA((it + 1) << 5);
            b_n = *(const bf16_8*)(Bp + ((it + 1) << 5));
        }
        bf16_8 a0 = *(const bf16_8*)&As[cur][moff + lrow][quad << 3];
        bf16_8 a1 = *(const bf16_8*)&As[cur][moff + 16 + lrow][quad << 3];
        bf16_8 b0 = *(const bf16_8*)&Bs[cur][noff + lrow][quad << 3];
        bf16_8 b1 = *(const bf16_8*)&Bs[cur][noff + 16 + lrow][quad << 3];
        acc00 = __builtin_amdgcn_mfma_f32_16x16x32_bf16(a0, b0, acc00, 0, 0, 0);
        acc01 = __builtin_amdgcn_mfma_f32_16x16x32_bf16(a0, b1, acc01, 0, 0, 0);
        acc10 = __builtin_amdgcn_mfma_f32_16x16x32_bf16(a1, b0, acc10, 0, 0, 0);
        acc11 = __builtin_amdgcn_mfma_f32_16x16x32_bf16(a1, b1, acc11, 0, 0, 0);
        if (it + 1 < nIter) {
            *(bf16_8*)&As[cur ^ 1][row][kc] = a_n;
            *(bf16_8*)&Bs[cur ^ 1][row][kc] = b_n;
            __syncthreads();
        }
    }

    const float* bias = p.bias[zi];
    f32x4_t accs[2][2] = {{acc00, acc01}, {acc10, acc11}};
#pragma unroll
    for (int ti = 0; ti < 2; ++ti) {
#pragma unroll
        for (int tj = 0; tj < 2; ++tj) {
            int colg = n0 + noff + (tj << 4) + lrow;
            float bv = bias[colg];
#pragma unroll
            for (int r = 0; r < 4; ++r) {
                int rowg = m0 + moff + (ti << 4) + (quad << 2) + r;
                float v = accs[ti][tj][r] + bv;
                if (GELU) v = 0.5f * v * (1.0f + erff(v * 0.70710678118654752f));
                if (OUTBF16)
                    ((__bf16*)p.C[zi])[(size_t)rowg * ldc + colg] = (__bf16)v;
                else
                    ((float*)p.C[zi])[(size_t)rowg * ldc + colg] = v;
            }
        }
    }
}

extern "C" void kernel_launch(void* const* d_in, const int* in_sizes, int n_in,
                              void* d_out, int out_size, void* d_ws, size_t ws_size,
                              hipStream_t stream) {
    const float* x_v  = (const float*)d_in[0];
    const float* x_a  = (const float*)d_in[1];
    const float* W1v  = (const float*)d_in[2];
    const float* b1v  = (const float*)d_in[3];
    const float* W1a  = (const float*)d_in[4];
    const float* b1a  = (const float*)d_in[5];
    const float* Wmv  = (const float*)d_in[6];
    const float* bmv  = (const float*)d_in[7];
    const float* Wma  = (const float*)d_in[8];
    const float* bma  = (const float*)d_in[9];
    const float* Wout = (const float*)d_in[10];
    const float* bout = (const float*)d_in[11];
    float* out = (float*)d_out;

    char* w = (char*)d_ws;
    auto alloc = [&](size_t bytes) {
        char* r = w;
        w += (bytes + 255) & ~(size_t)255;
        return (void*)r;
    };
    float*  dv    = (float*)alloc(512 * 4);
    float*  da    = (float*)alloc(512 * 4);
    __bf16* WT1v  = (__bf16*)alloc((size_t)Hdim * Ddim * 2);        // [2048][512]
    __bf16* WT1a  = (__bf16*)alloc((size_t)Hdim * Ddim * 2);
    __bf16* WTmv  = (__bf16*)alloc((size_t)Ddim * Hdim * 2);        // [512][2048]
    __bf16* WTma  = (__bf16*)alloc((size_t)Ddim * Hdim * 2);
    __bf16* WTout = (__bf16*)alloc((size_t)Ddim * 2 * Ddim * 2);    // [512][1024]
    __bf16* g1v   = (__bf16*)alloc((size_t)Mrows * Hdim * 2);       // [512][2048]
    __bf16* g1a   = (__bf16*)alloc((size_t)Mrows * Hdim * 2);
    __bf16* comb  = (__bf16*)alloc((size_t)Mrows * 2 * Ddim * 2);   // [512][1024]

    // 1) fused transpose+cast (blocks 0..4607) + distance means (4608..4863)
    PrepPtrs pp;
    pp.src[0] = W1v;  pp.dst[0] = WT1v;
    pp.src[1] = W1a;  pp.dst[1] = WT1a;
    pp.src[2] = Wmv;  pp.dst[2] = WTmv;
    pp.src[3] = Wma;  pp.dst[3] = WTma;
    pp.src[4] = Wout; pp.dst[4] = WTout;
    pp.xv = x_v; pp.xa = x_a; pp.dv = dv; pp.da = da;
    prep_kernel<<<dim3(4864), dim3(256), 0, stream>>>(pp);

    // 2) g1 = gelu(diag(d)*x @ W1 + b1)   [512,2048] bf16, z fuses v/a
    GPtrs g1;
    g1.A[0] = x_v; g1.A[1] = x_a;
    g1.BT[0] = WT1v; g1.BT[1] = WT1a;
    g1.bias[0] = b1v; g1.bias[1] = b1a;
    g1.scale[0] = dv; g1.scale[1] = da;
    g1.C[0] = g1v; g1.C[1] = g1a;
    mfma_gemm<1, 1, 1><<<dim3(Hdim / 64, Mrows / 64, 2), dim3(256), 0, stream>>>(
        g1, Ddim, Hdim);

    // 3) comb[:, :512] = g1v @ Wmv + bmv ; comb[:, 512:] = g1a @ Wma + bma
    GPtrs g2;
    g2.A[0] = g1v; g2.A[1] = g1a;
    g2.BT[0] = WTmv; g2.BT[1] = WTma;
    g2.bias[0] = bmv; g2.bias[1] = bma;
    g2.scale[0] = nullptr; g2.scale[1] = nullptr;
    g2.C[0] = comb; g2.C[1] = comb + Ddim;
    mfma_gemm<0, 0, 1><<<dim3(Ddim / 64, Mrows / 64, 2), dim3(256), 0, stream>>>(
        g2, Hdim, 2 * Ddim);

    // 4) out = comb @ Wout + bout   [512, 512] fp32
    GPtrs g3;
    g3.A[0] = comb; g3.A[1] = comb;
    g3.BT[0] = WTout; g3.BT[1] = WTout;
    g3.bias[0] = bout; g3.bias[1] = bout;
    g3.scale[0] = nullptr; g3.scale[1] = nullptr;
    g3.C[0] = out; g3.C[1] = out;
    mfma_gemm<0, 0, 0><<<dim3(Ddim / 64, Mrows / 64, 1), dim3(256), 0, stream>>>(
        g3, 2 * Ddim, Ddim);
}

// Round 4
// 151.302 us; speedup vs baseline: 1.1407x; 1.1407x over previous
//
#include <hip/hip_runtime.h>
#include <math.h>

#define Bsz  2
#define Ntok 256
#define Ddim 512
#define Hdim 2048
#define Mrows (Bsz * Ntok)   // 512

typedef __bf16 bf16_8 __attribute__((ext_vector_type(8)));
typedef __bf16 bf16_4 __attribute__((ext_vector_type(4)));
typedef float  f32x4_t __attribute__((ext_vector_type(4)));

// ---------------------------------------------------------------------------
// Fused prep kernel.
// Blocks [0, 4608):       weight transpose+cast fp32 [K][N] -> bf16 [N][K]
// Blocks [4608, 5632):    distance partial sums, j-split 4 ways.
//   pv[jc][m] = sum_{j in chunk} sum_d |xv[m,d]-xa[b,j,d]|   (role 0)
//   pa[jc][m] likewise with roles swapped.                    (role 1)
// GEMM1 sums the 4 chunks and multiplies by 1/256.
// ---------------------------------------------------------------------------
struct PrepPtrs {
    const float* src[5];
    __bf16*      dst[5];
    const float* xv;
    const float* xa;
    float*       pv;    // [4][512]
    float*       pa;    // [4][512]
};

__global__ __launch_bounds__(256) void prep_kernel(PrepPtrs p) {
    __shared__ float tile[32][33];
    __shared__ float red[4][4];

    int blk = blockIdx.x;
    int tid = threadIdx.x;

    if (blk < 4608) {
        // ---- transpose+cast ----
        const int Ks[5]  = {512, 512, 2048, 2048, 1024};
        const int Ns[5]  = {2048, 2048, 512, 512, 512};
        const int off[6] = {0, 1024, 2048, 3072, 4096, 4608};
        int mi = 0;
        while (blk >= off[mi + 1]) ++mi;
        int local = blk - off[mi];
        int shift = (mi < 2) ? 6 : 4;
        int bx = local & ((1 << shift) - 1);
        int by = local >> shift;
        const float* src = p.src[mi];
        __bf16*      dst = p.dst[mi];
        int K = Ks[mi], N = Ns[mi];
        int n0 = bx << 5, k0 = by << 5;

        int kl = tid >> 3, nl = (tid & 7) << 2;
        float4 v = *(const float4*)&src[(size_t)(k0 + kl) * N + n0 + nl];
        tile[kl][nl + 0] = v.x;
        tile[kl][nl + 1] = v.y;
        tile[kl][nl + 2] = v.z;
        tile[kl][nl + 3] = v.w;
        __syncthreads();
        int nl2 = tid >> 3, kl2 = (tid & 7) << 2;
        bf16_4 o;
#pragma unroll
        for (int i = 0; i < 4; ++i) o[i] = (__bf16)tile[kl2 + i][nl2];
        *(bf16_4*)&dst[(size_t)(n0 + nl2) * K + k0 + kl2] = o;
    } else {
        // ---- distance partials ----
        // block id: role(2) x batch(2) x igroup(64) x jchunk(4)
        int bx   = blk - 4608;
        int jc   = bx & 3;
        int g    = bx >> 2;            // 0..255
        int role = g >> 7;
        int b    = (g >> 6) & 1;
        int i0   = (g & 63) << 2;
        const float* Q    = role ? p.xa : p.xv;
        const float* S    = role ? p.xv : p.xa;
        float*       outp = role ? p.pa : p.pv;

        int d0 = tid << 1;             // thread owns cols d0, d0+1
        const float* Qb = Q + ((size_t)b * Ntok + i0) * Ddim + d0;
        const float* Sb = S + ((size_t)b * Ntok + (jc << 6)) * Ddim + d0;

        float2 q[4];
#pragma unroll
        for (int r = 0; r < 4; ++r) q[r] = *(const float2*)(Qb + r * Ddim);

        float acc[4] = {0.f, 0.f, 0.f, 0.f};
#pragma unroll 4
        for (int j = 0; j < 64; ++j) {
            float2 s = *(const float2*)(Sb + (size_t)j * Ddim);
#pragma unroll
            for (int r = 0; r < 4; ++r)
                acc[r] += fabsf(q[r].x - s.x) + fabsf(q[r].y - s.y);
        }
        int lane = tid & 63, wv = tid >> 6;
#pragma unroll
        for (int r = 0; r < 4; ++r) {
            float v = acc[r];
#pragma unroll
            for (int off2 = 32; off2; off2 >>= 1) v += __shfl_down(v, off2);
            if (lane == 0) red[wv][r] = v;
        }
        __syncthreads();
        if (tid < 4) {
            float v = red[0][tid] + red[1][tid] + red[2][tid] + red[3][tid];
            outp[jc * Mrows + b * Ntok + i0 + tid] = v;   // raw sum; /256 in GEMM1
        }
    }
}

// ---------------------------------------------------------------------------
// bf16 MFMA GEMM, 2-deep pipelined ping-pong LDS, 1 barrier/iter.
// Global loads for tile it+2 are issued in iter it (raw regs; fp32->bf16
// conversion deferred to the LDS-write phase) -> load->use distance ~1.5 iters.
// C[z] = act( (diag(scale[z]) * A[z]) @ B[z] + bias[z] )
// 64x64 tile, BK=32, 4 waves, each wave a 32x32 quadrant via 2x2 MFMA.
// ---------------------------------------------------------------------------
struct GPtrs {
    const void*   A[2];
    const __bf16* BT[2];
    const float*  bias[2];
    const float*  scale[2];   // GEMM1: partial sums [4][512]; else unused
    void*         C[2];
};

template <int AFP32>
struct StageA {
    float4 f0, f1;
};
template <>
struct StageA<0> {
    bf16_8 a8;
};

template <int GELU, int AFP32, int OUTBF16>
__global__ __launch_bounds__(256) void mfma_gemm(GPtrs p, int Kdim, int ldc) {
    __shared__ __align__(16) __bf16 As[2][64][40];
    __shared__ __align__(16) __bf16 Bs[2][64][40];

    const int zi  = blockIdx.z;
    const int tid = threadIdx.x;
    const int m0 = blockIdx.y << 6, n0 = blockIdx.x << 6;

    const int row = tid >> 2;        // 0..63
    const int kc  = (tid & 3) << 3;  // 0,8,16,24

    const __bf16* Bp = p.BT[zi] + (size_t)(n0 + row) * Kdim + kc;
    const float*  Afp = nullptr;
    const __bf16* Abp = nullptr;
    float s = 1.0f;
    if (AFP32) {
        Afp = (const float*)p.A[zi] + (size_t)(m0 + row) * Kdim + kc;
        const float* ps = p.scale[zi];
        int m = m0 + row;
        s = (ps[m] + ps[Mrows + m] + ps[2 * Mrows + m] + ps[3 * Mrows + m])
            * (1.0f / 256.0f);
    } else {
        Abp = (const __bf16*)p.A[zi] + (size_t)(m0 + row) * Kdim + kc;
    }

    const int wave = tid >> 6, lane = tid & 63;
    const int moff = (wave >> 1) << 5, noff = (wave & 1) << 5;
    const int lrow = lane & 15, quad = lane >> 4;

    auto loadStage = [&](int kt, StageA<AFP32>& st, bf16_8& bb) {
        bb = *(const bf16_8*)(Bp + kt);
        if constexpr (AFP32) {
            st.f0 = *(const float4*)(Afp + kt);
            st.f1 = *(const float4*)(Afp + kt + 4);
        } else {
            st.a8 = *(const bf16_8*)(Abp + kt);
        }
    };
    auto storeStage = [&](int buf, const StageA<AFP32>& st, const bf16_8& bb) {
        bf16_8 a8;
        if constexpr (AFP32) {
            a8[0] = (__bf16)(st.f0.x * s); a8[1] = (__bf16)(st.f0.y * s);
            a8[2] = (__bf16)(st.f0.z * s); a8[3] = (__bf16)(st.f0.w * s);
            a8[4] = (__bf16)(st.f1.x * s); a8[5] = (__bf16)(st.f1.y * s);
            a8[6] = (__bf16)(st.f1.z * s); a8[7] = (__bf16)(st.f1.w * s);
        } else {
            a8 = st.a8;
        }
        *(bf16_8*)&As[buf][row][kc] = a8;
        *(bf16_8*)&Bs[buf][row][kc] = bb;
    };

    f32x4_t acc00 = {0.f, 0.f, 0.f, 0.f};
    f32x4_t acc01 = {0.f, 0.f, 0.f, 0.f};
    f32x4_t acc10 = {0.f, 0.f, 0.f, 0.f};
    f32x4_t acc11 = {0.f, 0.f, 0.f, 0.f};

    const int nIter = Kdim >> 5;
    StageA<AFP32> stR, stN;   // staged (it+1) and in-flight (it+2)
    bf16_8 bR, bN;

    // prologue: stage tile 0 into LDS, issue tile 1
    {
        StageA<AFP32> st0; bf16_8 b0;
        loadStage(0, st0, b0);
        storeStage(0, st0, b0);
    }
    if (nIter > 1) loadStage(32, stR, bR);
    __syncthreads();

    for (int it = 0; it < nIter; ++it) {
        const int cur = it & 1;
        bf16_8 a0 = *(const bf16_8*)&As[cur][moff + lrow][quad << 3];
        bf16_8 a1 = *(const bf16_8*)&As[cur][moff + 16 + lrow][quad << 3];
        bf16_8 b0 = *(const bf16_8*)&Bs[cur][noff + lrow][quad << 3];
        bf16_8 b1 = *(const bf16_8*)&Bs[cur][noff + 16 + lrow][quad << 3];
        if (it + 2 < nIter) loadStage((it + 2) << 5, stN, bN);
        acc00 = __builtin_amdgcn_mfma_f32_16x16x32_bf16(a0, b0, acc00, 0, 0, 0);
        acc01 = __builtin_amdgcn_mfma_f32_16x16x32_bf16(a0, b1, acc01, 0, 0, 0);
        acc10 = __builtin_amdgcn_mfma_f32_16x16x32_bf16(a1, b0, acc10, 0, 0, 0);
        acc11 = __builtin_amdgcn_mfma_f32_16x16x32_bf16(a1, b1, acc11, 0, 0, 0);
        if (it + 1 < nIter) {
            storeStage(cur ^ 1, stR, bR);
            stR = stN; bR = bN;
            __syncthreads();
        }
    }

    const float* bias = p.bias[zi];
    f32x4_t accs[2][2] = {{acc00, acc01}, {acc10, acc11}};
#pragma unroll
    for (int ti = 0; ti < 2; ++ti) {
#pragma unroll
        for (int tj = 0; tj < 2; ++tj) {
            int colg = n0 + noff + (tj << 4) + lrow;
            float bv = bias[colg];
#pragma unroll
            for (int r = 0; r < 4; ++r) {
                int rowg = m0 + moff + (ti << 4) + (quad << 2) + r;
                float v = accs[ti][tj][r] + bv;
                if (GELU) v = 0.5f * v * (1.0f + erff(v * 0.70710678118654752f));
                if (OUTBF16)
                    ((__bf16*)p.C[zi])[(size_t)rowg * ldc + colg] = (__bf16)v;
                else
                    ((float*)p.C[zi])[(size_t)rowg * ldc + colg] = v;
            }
        }
    }
}

extern "C" void kernel_launch(void* const* d_in, const int* in_sizes, int n_in,
                              void* d_out, int out_size, void* d_ws, size_t ws_size,
                              hipStream_t stream) {
    const float* x_v  = (const float*)d_in[0];
    const float* x_a  = (const float*)d_in[1];
    const float* W1v  = (const float*)d_in[2];
    const float* b1v  = (const float*)d_in[3];
    const float* W1a  = (const float*)d_in[4];
    const float* b1a  = (const float*)d_in[5];
    const float* Wmv  = (const float*)d_in[6];
    const float* bmv  = (const float*)d_in[7];
    const float* Wma  = (const float*)d_in[8];
    const float* bma  = (const float*)d_in[9];
    const float* Wout = (const float*)d_in[10];
    const float* bout = (const float*)d_in[11];
    float* out = (float*)d_out;

    char* w = (char*)d_ws;
    auto alloc = [&](size_t bytes) {
        char* r = w;
        w += (bytes + 255) & ~(size_t)255;
        return (void*)r;
    };
    float*  pv    = (float*)alloc(4 * Mrows * 4);                   // [4][512]
    float*  pa    = (float*)alloc(4 * Mrows * 4);
    __bf16* WT1v  = (__bf16*)alloc((size_t)Hdim * Ddim * 2);        // [2048][512]
    __bf16* WT1a  = (__bf16*)alloc((size_t)Hdim * Ddim * 2);
    __bf16* WTmv  = (__bf16*)alloc((size_t)Ddim * Hdim * 2);        // [512][2048]
    __bf16* WTma  = (__bf16*)alloc((size_t)Ddim * Hdim * 2);
    __bf16* WTout = (__bf16*)alloc((size_t)Ddim * 2 * Ddim * 2);    // [512][1024]
    __bf16* g1v   = (__bf16*)alloc((size_t)Mrows * Hdim * 2);
    __bf16* g1a   = (__bf16*)alloc((size_t)Mrows * Hdim * 2);
    __bf16* comb  = (__bf16*)alloc((size_t)Mrows * 2 * Ddim * 2);   // [512][1024]

    // 1) transpose+cast (blocks 0..4607) + distance partials (4608..5631)
    PrepPtrs pp;
    pp.src[0] = W1v;  pp.dst[0] = WT1v;
    pp.src[1] = W1a;  pp.dst[1] = WT1a;
    pp.src[2] = Wmv;  pp.dst[2] = WTmv;
    pp.src[3] = Wma;  pp.dst[3] = WTma;
    pp.src[4] = Wout; pp.dst[4] = WTout;
    pp.xv = x_v; pp.xa = x_a; pp.pv = pv; pp.pa = pa;
    prep_kernel<<<dim3(5632), dim3(256), 0, stream>>>(pp);

    // 2) g1 = gelu(diag(d)*x @ W1 + b1)   [512,2048] bf16, z fuses v/a
    GPtrs g1;
    g1.A[0] = x_v; g1.A[1] = x_a;
    g1.BT[0] = WT1v; g1.BT[1] = WT1a;
    g1.bias[0] = b1v; g1.bias[1] = b1a;
    g1.scale[0] = pv; g1.scale[1] = pa;
    g1.C[0] = g1v; g1.C[1] = g1a;
    mfma_gemm<1, 1, 1><<<dim3(Hdim / 64, Mrows / 64, 2), dim3(256), 0, stream>>>(
        g1, Ddim, Hdim);

    // 3) comb[:, :512] = g1v @ Wmv + bmv ; comb[:, 512:] = g1a @ Wma + bma
    GPtrs g2;
    g2.A[0] = g1v; g2.A[1] = g1a;
    g2.BT[0] = WTmv; g2.BT[1] = WTma;
    g2.bias[0] = bmv; g2.bias[1] = bma;
    g2.scale[0] = nullptr; g2.scale[1] = nullptr;
    g2.C[0] = comb; g2.C[1] = comb + Ddim;
    mfma_gemm<0, 0, 1><<<dim3(Ddim / 64, Mrows / 64, 2), dim3(256), 0, stream>>>(
        g2, Hdim, 2 * Ddim);

    // 4) out = comb @ Wout + bout   [512, 512] fp32
    GPtrs g3;
    g3.A[0] = comb; g3.A[1] = comb;
    g3.BT[0] = WTout; g3.BT[1] = WTout;
    g3.bias[0] = bout; g3.bias[1] = bout;
    g3.scale[0] = nullptr; g3.scale[1] = nullptr;
    g3.C[0] = out; g3.C[1] = out;
    mfma_gemm<0, 0, 0><<<dim3(Ddim / 64, Mrows / 64, 1), dim3(256), 0, stream>>>(
        g3, 2 * Ddim, Ddim);
}